// Round 4
// baseline (884.940 us; speedup 1.0000x reference)
//
#include <hip/hip_runtime.h>

// CustomRNN: B=128, T=64, D=H=256, L=2, 3-node cell.
// Round 9: r7 structure (XCD co-location, ACQUIRE poll -- r8's RELAXED poll
// was a deadlock hazard: no cache-invalidate in the poll loop => consumer
// XCD L2 can spin on a stale flag line forever, esp. across graph replays).
// Kept from r8 (orthogonal, ledger-safe):
// (1) QUARTER-PREFETCH: 4 co-located CUs/XCD each dma16 a disjoint quarter
//     of the t+2 weight block into dump-LDS -> 4x miss parallelism; the
//     consumption DMAs then L2-hit. L0 drains them at publish waitvm<0>;
//     L1 drains them in the next loop-top acquire (during the flag spin).
// (2) transpose_cvt store phase: 32 consecutive lanes per 512B row.
// Ledger: L0 m0 phases NW 20->32, xw-wait 20->28, preludes waitvm<0>;
// consumer NW values identical to r7.

typedef _Float16 f16;
typedef __attribute__((ext_vector_type(8))) _Float16 f16x8;
typedef __attribute__((ext_vector_type(4))) float f32x4;
typedef __attribute__((ext_vector_type(4))) float float4v;

#define Tt 64
#define FLAG_MAGIC 0x52570000

// ---- workspace byte offsets ----
#define WS_WH0T   0
#define WS_WIN1T  25165824
#define WS_WH1T   33554432
#define WS_WIN0T  58720256
#define WS_XW     67108864
#define WS_HSEQ   75497472
#define WS_FLAGS  79691776

// ---------------- helpers ----------------
__device__ __forceinline__ void sb() { __builtin_amdgcn_sched_barrier(0); }

template <int N>
__device__ __forceinline__ void waitvm() {
  // s_waitcnt vmcnt(N), lgkm=15 (no wait), exp=7 (no wait); gfx9 encoding
  __builtin_amdgcn_s_waitcnt(0x0F70 | (N & 15) | ((N >> 4) << 14));
}
__device__ __forceinline__ void waitlgkm0() { __builtin_amdgcn_s_waitcnt(0xC07F); }

__device__ __forceinline__ void barx() {
  // barrier draining LDS ops only -- weight DMAs (vmcnt) stay in flight
  asm volatile("s_waitcnt lgkmcnt(0)\n\ts_barrier" ::: "memory");
}

__device__ __forceinline__ void dma16(const void* g, void* l) {
  __builtin_amdgcn_global_load_lds(
      (const __attribute__((address_space(1))) unsigned int*)g,
      (__attribute__((address_space(3))) unsigned int*)l, 16, 0, 0);
}

__device__ __forceinline__ float tanh_fast(float x) {
  float xc = fminf(fmaxf(x, -15.f), 15.f);
  float e = __expf(2.f * xc);
  return (e - 1.f) / (e + 1.f);
}
__device__ __forceinline__ float sigmoid_fast(float x) { return 1.f / (1.f + __expf(-x)); }

// ---------------- transpose+convert: [k][n] f32 -> [n][k] f16 ----------------
// 512 matrices: 192 Wh0 + 64 Win1 + 192 Wh1 + 64 Win0
__global__ __launch_bounds__(256) void transpose_cvt_kernel(
    const float* __restrict__ Wh0, const float* __restrict__ Win1,
    const float* __restrict__ Wh1, const float* __restrict__ Win0,
    f16* __restrict__ Wh0T, f16* __restrict__ Win1T, f16* __restrict__ Wh1T,
    f16* __restrict__ Win0T) {
  __shared__ float tile[256 * 33];
  const int bid = blockIdx.x;
  const int mat = bid >> 3, n0 = (bid & 7) << 5;
  const float* src; f16* dst;
  if (mat < 192)      { src = Wh0  + (size_t)mat * 65536;         dst = Wh0T  + (size_t)mat * 65536; }
  else if (mat < 256) { src = Win1 + (size_t)(mat - 192) * 65536; dst = Win1T + (size_t)(mat - 192) * 65536; }
  else if (mat < 448) { src = Wh1  + (size_t)(mat - 256) * 65536; dst = Wh1T  + (size_t)(mat - 256) * 65536; }
  else                { src = Win0 + (size_t)(mat - 448) * 65536; dst = Win0T + (size_t)(mat - 448) * 65536; }
  const int tid = threadIdx.x;
  const int c2 = tid & 15, kl = tid >> 4;
#pragma unroll
  for (int p = 0; p < 16; ++p) {
    const int k = kl + p * 16;
    float2 v = *(const float2*)(src + k * 256 + n0 + c2 * 2);
    tile[k * 33 + c2 * 2]     = v.x;
    tile[k * 33 + c2 * 2 + 1] = v.y;
  }
  __syncthreads();
  // store phase: 32 consecutive lanes cover one n-row's 512 contiguous bytes
  const int n = tid >> 5, c = tid & 31;
#pragma unroll
  for (int it = 0; it < 4; ++it) {
    const int nn = n + it * 8;
    f16x8 vv;
#pragma unroll
    for (int i = 0; i < 8; ++i) vv[i] = (f16)tile[(c * 8 + i) * 33 + nn];
    *(f16x8*)((char*)dst + (size_t)(n0 + nn) * 512 + c * 16) = vv;
  }
}

// ---------------- xw precompute: xw[t,b,h] = x[b,t,:]@Win0[t] + b0[t,0,h] ----
__global__ __launch_bounds__(512, 2) void xw_kernel(
    const float* __restrict__ x, const f16* __restrict__ Win0T,
    const float* __restrict__ b0, float* __restrict__ xw) {
  const int t = blockIdx.x >> 3, bb = blockIdx.x & 7;
  const int rb = bb << 4;
  const int tid = threadIdx.x, lane = tid & 63, w = tid >> 6;
  const int q = lane >> 4, mn = lane & 15, dr = q * 4;
  const f16* wt = Win0T + (size_t)t * 65536;
  const float4v* xr = (const float4v*)(x + ((size_t)(rb + mn) * Tt + t) * 256);
  f32x4 acc[2] = {{0.f,0.f,0.f,0.f},{0.f,0.f,0.f,0.f}};
#pragma unroll
  for (int kt = 0; kt < 8; ++kt) {
    const int k0 = kt * 32 + q * 8;
    float4v x0 = xr[k0 / 4], x1 = xr[k0 / 4 + 1];
    f16x8 a = {(f16)x0.x, (f16)x0.y, (f16)x0.z, (f16)x0.w,
               (f16)x1.x, (f16)x1.y, (f16)x1.z, (f16)x1.w};
#pragma unroll
    for (int nt = 0; nt < 2; ++nt) {
      f16x8 b = *(const f16x8*)(wt + (size_t)(w * 32 + nt * 16 + mn) * 256 + k0);
      acc[nt] = __builtin_amdgcn_mfma_f32_16x16x32_f16(a, b, acc[nt], 0, 0, 0);
    }
  }
#pragma unroll
  for (int nt = 0; nt < 2; ++nt) {
    const int n = w * 32 + nt * 16 + mn;
    const float bv = b0[(size_t)t * 768 + n];
#pragma unroll
    for (int r = 0; r < 4; ++r)
      xw[(size_t)t * 32768 + (size_t)(rb + dr + r) * 256 + n] = acc[nt][r] + bv;
  }
}

// ---------------- matmul K-half phase (A from LDS) ----------------
template <int NW, bool DMA>
__device__ __forceinline__ void phase(f32x4 (&acc)[2], const char* arow, const char* wb,
                                      const int (&bo)[4], const char* gnext, char* lnext,
                                      const int (&off)[8], int q) {
  waitvm<NW>();
  sb();
  f16x8 a[4], b[8];
#pragma unroll
  for (int kt = 0; kt < 4; ++kt) {
    a[kt]         = *(const f16x8*)(arow + kt * 64 + q * 16);
    b[kt * 2]     = *(const f16x8*)(wb + bo[kt]);
    b[kt * 2 + 1] = *(const f16x8*)(wb + bo[kt] + 4096);
  }
  sb();
  waitlgkm0();
  if (DMA) {
#pragma unroll
    for (int d = 0; d < 8; ++d) dma16(gnext + off[d], lnext + d * 1024);
  }
  sb();
#pragma unroll
  for (int kt = 0; kt < 4; ++kt) {
    acc[0] = __builtin_amdgcn_mfma_f32_16x16x32_f16(a[kt], b[kt * 2],     acc[0], 0, 0, 0);
    acc[1] = __builtin_amdgcn_mfma_f32_16x16x32_f16(a[kt], b[kt * 2 + 1], acc[1], 0, 0, 0);
  }
}

// ---------------- matmul K-half phase (A from registers) ----------------
template <int NW>
__device__ __forceinline__ void phaseRA(f32x4 (&acc)[2], const f16x8* af, const char* wb,
                                        const int (&bo)[4], const char* gnext, char* lnext,
                                        const int (&off)[8]) {
  waitvm<NW>();
  sb();
  f16x8 b[8];
#pragma unroll
  for (int kt = 0; kt < 4; ++kt) {
    b[kt * 2]     = *(const f16x8*)(wb + bo[kt]);
    b[kt * 2 + 1] = *(const f16x8*)(wb + bo[kt] + 4096);
  }
  sb();
  waitlgkm0();
#pragma unroll
  for (int d = 0; d < 8; ++d) dma16(gnext + off[d], lnext + d * 1024);
  sb();
#pragma unroll
  for (int kt = 0; kt < 4; ++kt) {
    acc[0] = __builtin_amdgcn_mfma_f32_16x16x32_f16(af[kt], b[kt * 2],     acc[0], 0, 0, 0);
    acc[1] = __builtin_amdgcn_mfma_f32_16x16x32_f16(af[kt], b[kt * 2 + 1], acc[1], 0, 0, 0);
  }
}

// ---------------- recurrent kernel: grid 32, 16 active (8 L0 + 8 L1) -------
// blockIdx%8 = XCD. L0 -> XCDs {0,1} (4 CUs each), L1 -> XCDs {4,5}.
// slot = blockIdx>>3 (0..3) = prefetch-quarter owner within the XCD.
__global__ __launch_bounds__(512, 1) void rnn_kernel(
    const float* __restrict__ hidden,
    const f16* __restrict__ Wh0T, const float* __restrict__ b0,
    const f16* __restrict__ Win1T, const f16* __restrict__ Wh1T, const float* __restrict__ b1,
    const float* __restrict__ xw, f16* __restrict__ hseq, int* __restrict__ flags,
    float* __restrict__ out) {
  __shared__ __align__(16) char smem[148992];
  char* wlds = smem;                 // 8 waves x 16 KB
  char* abuf = smem + 131072;        // recurrent h
  char* nbuf = smem + 139520;
  char* dump = smem + 147968;        // 1 KB prefetch dump (never read)

  // ---- XCD-aware role/group mapping ----
  const int xcd = blockIdx.x & 7, slot = blockIdx.x >> 3;   // bid%8 -> XCD
  bool isL0; int g;
  if (xcd < 2)                  { isL0 = true;  g = xcd * 4 + slot; }        // XCD 0,1
  else if (xcd >= 4 && xcd < 6) { isL0 = false; g = (xcd - 4) * 4 + slot; }  // XCD 4,5
  else return;

  const int tid = threadIdx.x;
  const int lane = tid & 63;
  const int w = tid >> 6;
  const int q = lane >> 4;
  const int mn = lane & 15;
  const int rb = g << 4;
  const int nc = w * 32 + mn;
  const int dr = q * 4;
  const int wslice = w * 16384;

  int off[8], bo[4];
#pragma unroll
  for (int d = 0; d < 8; ++d) {
    const int row = 4 * d + q;
    off[d] = row * 512 + ((mn ^ (row & 15)) << 4);
  }
#pragma unroll
  for (int kt = 0; kt < 4; ++kt)
    bo[kt] = mn * 256 + (((kt * 4 + q) ^ mn) << 4);

  // init recurrent state (layer-appropriate half of hidden)
  const float* hsrc = hidden + (isL0 ? 0 : 32768) + (size_t)rb * 256;
  for (int i = tid; i < 16 * 256; i += 512) {
    const int m = i >> 8, n = i & 255;
    *(f16*)(abuf + m * 528 + n * 2) = (f16)hsrc[m * 256 + n];
  }

  char* bufA = wlds + wslice;
  char* bufB = bufA + 8192;
  const f32x4 zero4 = {0.f, 0.f, 0.f, 0.f};
  float n0v[2][4], n1v[2][4];

  if (isL0) {
    // =================== LAYER-0 PRODUCER ===================
    const char* WB = (const char*)Wh0T;   // [t][3][256][256] f16 (transposed)
    { // prelude: DMA Wh0[0](t=0) halves, then drain (residency for t=0)
      const char* gw = WB + wslice;
#pragma unroll
      for (int d = 0; d < 8; ++d) dma16(gw + off[d], bufA + d * 1024);
#pragma unroll
      for (int d = 0; d < 8; ++d) dma16(gw + 256 + off[d], bufB + d * 1024);
      sb();
      waitvm<0>();
    }
    barx();

#pragma unroll 1
    for (int t = 0; t < Tt; ++t) {
      const int tn = (t < Tt - 1) ? t + 1 : t;
      const bool last = (t == Tt - 1);
      const char* wt  = WB + (size_t)t * 393216 + wslice;
      const char* wtn = WB + (size_t)tn * 393216 + wslice;

      // loop top: xw(t) [8 loads] + bias [4 loads]
      float xwv[2][4];
#pragma unroll
      for (int nt = 0; nt < 2; ++nt)
#pragma unroll
        for (int r = 0; r < 4; ++r)
          xwv[nt][r] = xw[(size_t)t * 32768 + (size_t)(rb + dr + r) * 256 + nc + nt * 16];
      const float bv1a = b0[(size_t)t * 768 + 256 + nc], bv1b = b0[(size_t)t * 768 + 256 + nc + 16];
      const float bv2a = b0[(size_t)t * 768 + 512 + nc], bv2b = b0[(size_t)t * 768 + 512 + nc + 16];
      sb();
      // prefetch quarter of Wh0(t+2) into dump LDS (12 dma16/wave, newest;
      // retired by this t's publish waitvm<0>)
      {
        const int t2 = (t + 2 < Tt) ? t + 2 : Tt - 1;
        const char* pfb = WB + (size_t)t2 * 393216 + slot * 98304 + w * 12288 + lane * 16;
#pragma unroll
        for (int i = 0; i < 12; ++i) dma16(pfb + i * 1024, dump);
      }
      sb();

      f32x4 acc[2];
      // ---- m0: n0 = tanh(h0@Wh0[0] + xw) ; prefetch Wh0[1]
      // FIFO at m0A: [bufA-pf 8][bufB-pf 8][xw 8][bias 4][pf 12] = 40
      //   -> NW=32 forces bufA-pf (t=0: prelude already drained; no-op)
      acc[0] = zero4; acc[1] = zero4;
      phase<32, true>(acc, abuf + mn * 528,       bufA, bo, wt + 131072,       bufA, off, q);
      phase<32, true>(acc, abuf + mn * 528 + 256, bufB, bo, wt + 131072 + 256, bufB, off, q);
      // xw landed: FIFO [xw 8][bias 4][pf 12][m1A 8][m1B 8] = 40 -> NW=28
      waitvm<28>();
      sb();
#pragma unroll
      for (int nt = 0; nt < 2; ++nt)
#pragma unroll
        for (int r = 0; r < 4; ++r) {
          float v = tanh_fast(acc[nt][r] + xwv[nt][r]);
          n0v[nt][r] = v;
          *(f16*)(nbuf + (dr + r) * 528 + (nc + nt * 16) * 2) = (f16)v;
        }
      barx();  // (1) n0 visible

      // ---- m1: n1 = relu(n0@Wh0[1] + b0[1]) + n0 ; prefetch Wh0[2]
      acc[0] = zero4; acc[1] = zero4;
      phase<8, true>(acc, nbuf + mn * 528,       bufA, bo, wt + 262144,       bufA, off, q);
      phase<8, true>(acc, nbuf + mn * 528 + 256, bufB, bo, wt + 262144 + 256, bufB, off, q);
      barx();  // (2) n0 reads done (WAR)
#pragma unroll
      for (int nt = 0; nt < 2; ++nt) {
        const float bv = nt ? bv1b : bv1a;
#pragma unroll
        for (int r = 0; r < 4; ++r) {
          float v = fmaxf(acc[nt][r] + bv, 0.f) + n0v[nt][r];
          n1v[nt][r] = v;
          *(f16*)(nbuf + (dr + r) * 528 + (nc + nt * 16) * 2) = (f16)v;
        }
      }
      barx();  // (3) n1 visible

      // ---- m2: n2 = sigmoid(n1@Wh0[2] + b0[2]) + n0 ; h0' = 0.5(n1+n2); no DMA
      acc[0] = zero4; acc[1] = zero4;
      phase<8, false>(acc, nbuf + mn * 528,       bufA, bo, wt, bufA, off, q);
      phase<0, false>(acc, nbuf + mn * 528 + 256, bufB, bo, wt, bufB, off, q);
      // epi: write h0' to abuf (LDS) + hseq (global), publish flag
#pragma unroll
      for (int nt = 0; nt < 2; ++nt) {
        const float bv = nt ? bv2b : bv2a;
#pragma unroll
        for (int r = 0; r < 4; ++r) {
          float s = sigmoid_fast(acc[nt][r] + bv);
          float hv = 0.5f * (n1v[nt][r] + s + n0v[nt][r]);
          f16 h16 = (f16)hv;
          *(f16*)(abuf + (dr + r) * 528 + (nc + nt * 16) * 2) = h16;
          hseq[((size_t)(g * 64 + t)) * 4096 + (dr + r) * 256 + nc + nt * 16] = h16;
          if (last) out[2097152 + (size_t)(rb + dr + r) * 256 + nc + nt * 16] = hv;
        }
      }
      waitvm<0>();          // all hseq stores (and dump pf) complete
      __threadfence();      // device-scope release of data
      __syncthreads();      // all waves' stores complete
      if (tid == 0) {
        __hip_atomic_store(&flags[g * 64 + t], FLAG_MAGIC | (t + 1),
                           __ATOMIC_RELEASE, __HIP_MEMORY_SCOPE_AGENT);
      }
      sb();
      // prefetch next step's Wh0[0] halves
      {
        const char* gw = wtn;
#pragma unroll
        for (int d = 0; d < 8; ++d) dma16(gw + off[d], bufA + d * 1024);
#pragma unroll
        for (int d = 0; d < 8; ++d) dma16(gw + 256 + off[d], bufB + d * 1024);
        sb();
      }
    }
  } else {
    // =================== LAYER-1 CONSUMER ===================
    const char* WI = (const char*)Win1T;  // [t][256][256]
    const char* WH = (const char*)Wh1T;   // [t][3][256][256]
    const f16* hsg = hseq + (size_t)g * 64 * 4096;
    { // prelude: DMA Wh1[0](t=0) halves, then drain (residency for t=0)
      const char* gw = WH + wslice;
#pragma unroll
      for (int d = 0; d < 8; ++d) dma16(gw + off[d], bufA + d * 1024);
#pragma unroll
      for (int d = 0; d < 8; ++d) dma16(gw + 256 + off[d], bufB + d * 1024);
      sb();
      waitvm<0>();
    }
    barx();

#pragma unroll 1
    for (int t = 0; t < Tt; ++t) {
      const int tn = (t < Tt - 1) ? t + 1 : t;
      const bool last = (t == Tt - 1);
      const char* wit = WI + (size_t)t * 131072 + wslice;
      const char* wht = WH + (size_t)t * 393216 + wslice;
      const char* whn = WH + (size_t)tn * 393216 + wslice;

      // poll producer flag -- ACQUIRE (proven r5/r7): the per-poll cache
      // invalidate is what makes the remote XCD's release store visible.
      // Implicit vmcnt drain retires last t's dump prefetches during the
      // spin (free -- producer is the lagging side).
      {
        const int want = FLAG_MAGIC | (t + 1);
        while (__hip_atomic_load(&flags[g * 64 + t], __ATOMIC_ACQUIRE,
                                 __HIP_MEMORY_SCOPE_AGENT) != want) {}
      }
      sb();
      // A-fragments of h0'(t) straight from global [8 dwordx4] + biases [6]
      const char* ht = (const char*)(hsg + (size_t)t * 4096);
      f16x8 af[8];
#pragma unroll
      for (int kt = 0; kt < 8; ++kt)
        af[kt] = *(const f16x8*)(ht + mn * 512 + kt * 64 + q * 16);
      const float bv0a = b1[(size_t)t * 768 + nc],       bv0b = b1[(size_t)t * 768 + nc + 16];
      const float bv1a = b1[(size_t)t * 768 + 256 + nc], bv1b = b1[(size_t)t * 768 + 256 + nc + 16];
      const float bv2a = b1[(size_t)t * 768 + 512 + nc], bv2b = b1[(size_t)t * 768 + 512 + nc + 16];
      sb();

      f32x4 acc[2];
      acc[0] = zero4; acc[1] = zero4;
      // ---- m4 first (hides handoff): h1@Wh1[0] ; prefetch Win1
      phase<63, true>(acc, abuf + mn * 528,       bufA, bo, wit,       bufA, off, q);
      phase<63, true>(acc, abuf + mn * 528 + 256, bufB, bo, wit + 256, bufB, off, q);
      // ---- m3: h0'@Win1 (A from regs) ; prefetch Wh1[1]
      phaseRA<8>(acc, af,     bufA, bo, wht + 131072,       bufA, off);
      phaseRA<8>(acc, af + 4, bufB, bo, wht + 131072 + 256, bufB, off);
#pragma unroll
      for (int nt = 0; nt < 2; ++nt) {
        const float bv = nt ? bv0b : bv0a;
#pragma unroll
        for (int r = 0; r < 4; ++r) {
          float v = tanh_fast(acc[nt][r] + bv);
          n0v[nt][r] = v;
          *(f16*)(nbuf + (dr + r) * 528 + (nc + nt * 16) * 2) = (f16)v;
        }
      }
      barx();  // (1) n0' visible

      // ---- m5: n1' = relu(n0'@Wh1[1] + b1[1]) + n0' ; prefetch Wh1[2]
      acc[0] = zero4; acc[1] = zero4;
      phase<8, true>(acc, nbuf + mn * 528,       bufA, bo, wht + 262144,       bufA, off, q);
      phase<8, true>(acc, nbuf + mn * 528 + 256, bufB, bo, wht + 262144 + 256, bufB, off, q);
      barx();  // (2) n0' reads done (WAR)
#pragma unroll
      for (int nt = 0; nt < 2; ++nt) {
        const float bv = nt ? bv1b : bv1a;
#pragma unroll
        for (int r = 0; r < 4; ++r) {
          float v = fmaxf(acc[nt][r] + bv, 0.f) + n0v[nt][r];
          n1v[nt][r] = v;
          *(f16*)(nbuf + (dr + r) * 528 + (nc + nt * 16) * 2) = (f16)v;
        }
      }
      barx();  // (3) n1' visible

      // ---- m6: n2' = sigmoid(n1'@Wh1[2] + b1[2]) + n0' ; h1' = 0.5(n1'+n2');
      //          prefetch next step's Wh1[0]
      acc[0] = zero4; acc[1] = zero4;
      phase<8, true>(acc, nbuf + mn * 528,       bufA, bo, whn,       bufA, off, q);
      phase<8, true>(acc, nbuf + mn * 528 + 256, bufB, bo, whn + 256, bufB, off, q);
#pragma unroll
      for (int nt = 0; nt < 2; ++nt) {
        const float bv = nt ? bv2b : bv2a;
#pragma unroll
        for (int r = 0; r < 4; ++r) {
          float s = sigmoid_fast(acc[nt][r] + bv);
          float hv = 0.5f * (n1v[nt][r] + s + n0v[nt][r]);
          *(f16*)(abuf + (dr + r) * 528 + (nc + nt * 16) * 2) = (f16)hv;
          out[((size_t)(rb + dr + r) * Tt + t) * 256 + nc + nt * 16] = hv;
          if (last) out[2097152 + 32768 + (size_t)(rb + dr + r) * 256 + nc + nt * 16] = hv;
        }
      }
      // prefetch quarter of Wh1(t+2)+Win1(t+2) into dump LDS (16 dma16/wave;
      // retired by the next loop-top acquire drain, during the flag spin)
      {
        const int t2 = (t + 2 < Tt) ? t + 2 : Tt - 1;
        const char* pfh = WH + (size_t)t2 * 393216 + slot * 98304 + w * 12288 + lane * 16;
#pragma unroll
        for (int i = 0; i < 12; ++i) dma16(pfh + i * 1024, dump);
        const char* pfi = WI + (size_t)t2 * 131072 + slot * 32768 + w * 4096 + lane * 16;
#pragma unroll
        for (int i = 0; i < 4; ++i) dma16(pfi + i * 1024, dump);
      }
      sb();
      barx();  // (4) step end: h1' visible, nbuf reads done
    }
  }
}

// ---------------- launch ----------------
extern "C" void kernel_launch(void* const* d_in, const int* in_sizes, int n_in,
                              void* d_out, int out_size, void* d_ws, size_t ws_size,
                              hipStream_t stream) {
  (void)in_sizes; (void)n_in; (void)out_size; (void)ws_size;
  const float* x      = (const float*)d_in[0];
  const float* hidden = (const float*)d_in[1];
  const float* Win0   = (const float*)d_in[2];
  const float* Wh0    = (const float*)d_in[3];
  const float* b0     = (const float*)d_in[4];
  const float* Win1   = (const float*)d_in[5];
  const float* Wh1    = (const float*)d_in[6];
  const float* b1     = (const float*)d_in[7];
  float* out = (float*)d_out;

  char* ws = (char*)d_ws;
  f16* Wh0T  = (f16*)(ws + WS_WH0T);
  f16* Win1T = (f16*)(ws + WS_WIN1T);
  f16* Wh1T  = (f16*)(ws + WS_WH1T);
  f16* Win0T = (f16*)(ws + WS_WIN0T);
  float* xwp = (float*)(ws + WS_XW);
  f16* hseq  = (f16*)(ws + WS_HSEQ);
  int* flags = (int*)(ws + WS_FLAGS);

  transpose_cvt_kernel<<<dim3(4096), dim3(256), 0, stream>>>(
      Wh0, Win1, Wh1, Win0, Wh0T, Win1T, Wh1T, Win0T);
  xw_kernel<<<dim3(512), dim3(512), 0, stream>>>(x, Win0T, b0, xwp);
  rnn_kernel<<<dim3(32), dim3(512), 0, stream>>>(
      hidden, Wh0T, b0, Win1T, Wh1T, b1, xwp, hseq, flags, out);
}

// Round 5
// 804.540 us; speedup vs baseline: 1.0999x; 1.0999x over previous
//
#include <hip/hip_runtime.h>

// CustomRNN: B=128, T=64, D=H=256, L=2, 3-node cell.
// Round 10: r5 structure (16 WGs default mapping, acquire handoff) with the
// pipeline REBALANCED. Evidence r7/r9: per-CU ingest cap (~23-30 B/cyc) is
// CU-internal; co-location and miss-parallelism both regressed. Only lever
// that works: bytes/CU. r5 was lopsided (L0 384KB/t, L1 512KB/t). Move m3
// (h0'@Win1) to the PRODUCER: L0 has h0' in LDS anyway, streams Win1 itself
// (512KB/t), and publishes the f32 partial p3 = h0'@Win1 + b1[0] (16KB/t).
// Consumer drops to 384KB/t and runs m4 BEFORE the poll (m4 needs nothing
// from the producer) so handoff latency hides behind compute.
// No new sync: same one flag per (g,t), same proven release/acquire.
// Kept (verified r7/r9): Win0T f16 transpose, vector xw_kernel, contiguous
// transpose stores. Dropped (proven negative): co-location, quarter-prefetch.

typedef _Float16 f16;
typedef __attribute__((ext_vector_type(8))) _Float16 f16x8;
typedef __attribute__((ext_vector_type(4))) float f32x4;
typedef __attribute__((ext_vector_type(4))) float float4v;

#define Tt 64
#define FLAG_MAGIC 0x52570000

// ---- workspace byte offsets ----
// Wh0T f16 25,165,824 | Win1T f16 8,388,608 | Wh1T f16 25,165,824
// Win0T f16 8,388,608 | xw f32 8,388,608 | p3 f32 8,388,608 | flags 2,048
#define WS_WH0T   0
#define WS_WIN1T  25165824
#define WS_WH1T   33554432
#define WS_WIN0T  58720256
#define WS_XW     67108864
#define WS_P3     75497472
#define WS_FLAGS  83886080

// ---------------- helpers ----------------
__device__ __forceinline__ void sb() { __builtin_amdgcn_sched_barrier(0); }

template <int N>
__device__ __forceinline__ void waitvm() {
  // s_waitcnt vmcnt(N), lgkm=15 (no wait), exp=7 (no wait); gfx9 encoding
  __builtin_amdgcn_s_waitcnt(0x0F70 | (N & 15) | ((N >> 4) << 14));
}
__device__ __forceinline__ void waitlgkm0() { __builtin_amdgcn_s_waitcnt(0xC07F); }

__device__ __forceinline__ void barx() {
  // barrier draining LDS ops only -- weight DMAs (vmcnt) stay in flight
  asm volatile("s_waitcnt lgkmcnt(0)\n\ts_barrier" ::: "memory");
}

__device__ __forceinline__ void dma16(const void* g, void* l) {
  __builtin_amdgcn_global_load_lds(
      (const __attribute__((address_space(1))) unsigned int*)g,
      (__attribute__((address_space(3))) unsigned int*)l, 16, 0, 0);
}

__device__ __forceinline__ float tanh_fast(float x) {
  float xc = fminf(fmaxf(x, -15.f), 15.f);
  float e = __expf(2.f * xc);
  return (e - 1.f) / (e + 1.f);
}
__device__ __forceinline__ float sigmoid_fast(float x) { return 1.f / (1.f + __expf(-x)); }

// ---------------- transpose+convert: [k][n] f32 -> [n][k] f16 ----------------
// 512 matrices: 192 Wh0 + 64 Win1 + 192 Wh1 + 64 Win0
__global__ __launch_bounds__(256) void transpose_cvt_kernel(
    const float* __restrict__ Wh0, const float* __restrict__ Win1,
    const float* __restrict__ Wh1, const float* __restrict__ Win0,
    f16* __restrict__ Wh0T, f16* __restrict__ Win1T, f16* __restrict__ Wh1T,
    f16* __restrict__ Win0T) {
  __shared__ float tile[256 * 33];
  const int bid = blockIdx.x;
  const int mat = bid >> 3, n0 = (bid & 7) << 5;
  const float* src; f16* dst;
  if (mat < 192)      { src = Wh0  + (size_t)mat * 65536;         dst = Wh0T  + (size_t)mat * 65536; }
  else if (mat < 256) { src = Win1 + (size_t)(mat - 192) * 65536; dst = Win1T + (size_t)(mat - 192) * 65536; }
  else if (mat < 448) { src = Wh1  + (size_t)(mat - 256) * 65536; dst = Wh1T  + (size_t)(mat - 256) * 65536; }
  else                { src = Win0 + (size_t)(mat - 448) * 65536; dst = Win0T + (size_t)(mat - 448) * 65536; }
  const int tid = threadIdx.x;
  const int c2 = tid & 15, kl = tid >> 4;
#pragma unroll
  for (int p = 0; p < 16; ++p) {
    const int k = kl + p * 16;
    float2 v = *(const float2*)(src + k * 256 + n0 + c2 * 2);
    tile[k * 33 + c2 * 2]     = v.x;
    tile[k * 33 + c2 * 2 + 1] = v.y;
  }
  __syncthreads();
  // store phase: 32 consecutive lanes cover one n-row's 512 contiguous bytes
  const int n = tid >> 5, c = tid & 31;
#pragma unroll
  for (int it = 0; it < 4; ++it) {
    const int nn = n + it * 8;
    f16x8 vv;
#pragma unroll
    for (int i = 0; i < 8; ++i) vv[i] = (f16)tile[(c * 8 + i) * 33 + nn];
    *(f16x8*)((char*)dst + (size_t)(n0 + nn) * 512 + c * 16) = vv;
  }
}

// ---------------- xw precompute: xw[t,b,h] = x[b,t,:]@Win0[t] + b0[t,0,h] ----
__global__ __launch_bounds__(512, 2) void xw_kernel(
    const float* __restrict__ x, const f16* __restrict__ Win0T,
    const float* __restrict__ b0, float* __restrict__ xw) {
  const int t = blockIdx.x >> 3, bb = blockIdx.x & 7;
  const int rb = bb << 4;
  const int tid = threadIdx.x, lane = tid & 63, w = tid >> 6;
  const int q = lane >> 4, mn = lane & 15, dr = q * 4;
  const f16* wt = Win0T + (size_t)t * 65536;
  const float4v* xr = (const float4v*)(x + ((size_t)(rb + mn) * Tt + t) * 256);
  f32x4 acc[2] = {{0.f,0.f,0.f,0.f},{0.f,0.f,0.f,0.f}};
#pragma unroll
  for (int kt = 0; kt < 8; ++kt) {
    const int k0 = kt * 32 + q * 8;
    float4v x0 = xr[k0 / 4], x1 = xr[k0 / 4 + 1];
    f16x8 a = {(f16)x0.x, (f16)x0.y, (f16)x0.z, (f16)x0.w,
               (f16)x1.x, (f16)x1.y, (f16)x1.z, (f16)x1.w};
#pragma unroll
    for (int nt = 0; nt < 2; ++nt) {
      f16x8 b = *(const f16x8*)(wt + (size_t)(w * 32 + nt * 16 + mn) * 256 + k0);
      acc[nt] = __builtin_amdgcn_mfma_f32_16x16x32_f16(a, b, acc[nt], 0, 0, 0);
    }
  }
#pragma unroll
  for (int nt = 0; nt < 2; ++nt) {
    const int n = w * 32 + nt * 16 + mn;
    const float bv = b0[(size_t)t * 768 + n];
#pragma unroll
    for (int r = 0; r < 4; ++r)
      xw[(size_t)t * 32768 + (size_t)(rb + dr + r) * 256 + n] = acc[nt][r] + bv;
  }
}

// ---------------- matmul K-half phase (A from LDS) ----------------
template <int NW, bool DMA>
__device__ __forceinline__ void phase(f32x4 (&acc)[2], const char* arow, const char* wb,
                                      const int (&bo)[4], const char* gnext, char* lnext,
                                      const int (&off)[8], int q) {
  waitvm<NW>();
  sb();
  f16x8 a[4], b[8];
#pragma unroll
  for (int kt = 0; kt < 4; ++kt) {
    a[kt]         = *(const f16x8*)(arow + kt * 64 + q * 16);
    b[kt * 2]     = *(const f16x8*)(wb + bo[kt]);
    b[kt * 2 + 1] = *(const f16x8*)(wb + bo[kt] + 4096);
  }
  sb();
  waitlgkm0();
  if (DMA) {
#pragma unroll
    for (int d = 0; d < 8; ++d) dma16(gnext + off[d], lnext + d * 1024);
  }
  sb();
#pragma unroll
  for (int kt = 0; kt < 4; ++kt) {
    acc[0] = __builtin_amdgcn_mfma_f32_16x16x32_f16(a[kt], b[kt * 2],     acc[0], 0, 0, 0);
    acc[1] = __builtin_amdgcn_mfma_f32_16x16x32_f16(a[kt], b[kt * 2 + 1], acc[1], 0, 0, 0);
  }
}

// ---------------- recurrent kernel: 16 WGs (8 L0 + 8 L1), 16 rows each ------
__global__ __launch_bounds__(512, 1) void rnn_kernel(
    const float* __restrict__ hidden,
    const f16* __restrict__ Wh0T, const float* __restrict__ b0,
    const f16* __restrict__ Win1T, const f16* __restrict__ Wh1T, const float* __restrict__ b1,
    const float* __restrict__ xw, float* __restrict__ p3seq, int* __restrict__ flags,
    float* __restrict__ out) {
  __shared__ __align__(16) char smem[147968];
  char* wlds = smem;                 // 8 waves x 16 KB
  char* abuf = smem + 131072;        // recurrent h (h0 for L0 / h1 for L1)
  char* nbuf = smem + 139520;

  const int tid = threadIdx.x;
  const int lane = tid & 63;
  const int w = tid >> 6;
  const int q = lane >> 4;
  const int mn = lane & 15;
  const bool isL0 = blockIdx.x < 8;
  const int g = blockIdx.x & 7;
  const int rb = g << 4;
  const int nc = w * 32 + mn;
  const int dr = q * 4;
  const int wslice = w * 16384;

  int off[8], bo[4];
#pragma unroll
  for (int d = 0; d < 8; ++d) {
    const int row = 4 * d + q;
    off[d] = row * 512 + ((mn ^ (row & 15)) << 4);
  }
#pragma unroll
  for (int kt = 0; kt < 4; ++kt)
    bo[kt] = mn * 256 + (((kt * 4 + q) ^ mn) << 4);

  // init recurrent state (layer-appropriate half of hidden)
  const float* hsrc = hidden + (isL0 ? 0 : 32768) + (size_t)rb * 256;
  for (int i = tid; i < 16 * 256; i += 512) {
    const int m = i >> 8, n = i & 255;
    *(f16*)(abuf + m * 528 + n * 2) = (f16)hsrc[m * 256 + n];
  }

  char* bufA = wlds + wslice;
  char* bufB = bufA + 8192;
  const f32x4 zero4 = {0.f, 0.f, 0.f, 0.f};
  float n0v[2][4], n1v[2][4];

  if (isL0) {
    // =================== LAYER-0 PRODUCER (512 KB/t) ===================
    const char* WB = (const char*)Wh0T;   // [t][3][256][256] f16 (transposed)
    const char* WI = (const char*)Win1T;  // [t][256][256]
    { // prelude: DMA Wh0[0](t=0) halves
      const char* gw = WB + wslice;
#pragma unroll
      for (int d = 0; d < 8; ++d) dma16(gw + off[d], bufA + d * 1024);
#pragma unroll
      for (int d = 0; d < 8; ++d) dma16(gw + 256 + off[d], bufB + d * 1024);
      sb();
    }
    barx();

#pragma unroll 1
    for (int t = 0; t < Tt; ++t) {
      const int tn = (t < Tt - 1) ? t + 1 : t;
      const bool last = (t == Tt - 1);
      const char* wt  = WB + (size_t)t * 393216 + wslice;
      const char* wtn = WB + (size_t)tn * 393216 + wslice;
      const char* wit = WI + (size_t)t * 131072 + wslice;

      // loop top: xw(t) [8] + Wh0 biases [4] + Win1 bias row [2] = 14 loads
      float xwv[2][4];
#pragma unroll
      for (int nt = 0; nt < 2; ++nt)
#pragma unroll
        for (int r = 0; r < 4; ++r)
          xwv[nt][r] = xw[(size_t)t * 32768 + (size_t)(rb + dr + r) * 256 + nc + nt * 16];
      const float bv1a = b0[(size_t)t * 768 + 256 + nc], bv1b = b0[(size_t)t * 768 + 256 + nc + 16];
      const float bv2a = b0[(size_t)t * 768 + 512 + nc], bv2b = b0[(size_t)t * 768 + 512 + nc + 16];
      const float p3ba = b1[(size_t)t * 768 + nc],       p3bb = b1[(size_t)t * 768 + nc + 16];
      sb();

      f32x4 acc[2];
      // ---- m0: n0 = tanh(h0@Wh0[0] + xw) ; prefetch Wh0[1]
      // FIFO at m0A: [W0A 8][W0B 8][loads 14] = 30 -> NW=22 retires W0A
      acc[0] = zero4; acc[1] = zero4;
      phase<22, true>(acc, abuf + mn * 528,       bufA, bo, wt + 131072,       bufA, off, q);
      phase<22, true>(acc, abuf + mn * 528 + 256, bufB, bo, wt + 131072 + 256, bufB, off, q);
      // retire the 14 loads: [loads 14][W1A 8][W1B 8] = 30 -> NW=16
      waitvm<16>();
      sb();
#pragma unroll
      for (int nt = 0; nt < 2; ++nt)
#pragma unroll
        for (int r = 0; r < 4; ++r) {
          float v = tanh_fast(acc[nt][r] + xwv[nt][r]);
          n0v[nt][r] = v;
          *(f16*)(nbuf + (dr + r) * 528 + (nc + nt * 16) * 2) = (f16)v;
        }
      barx();  // (1) n0 visible

      // ---- m1: n1 = relu(n0@Wh0[1] + b0[1]) + n0 ; prefetch Wh0[2]
      acc[0] = zero4; acc[1] = zero4;
      phase<8, true>(acc, nbuf + mn * 528,       bufA, bo, wt + 262144,       bufA, off, q);
      phase<8, true>(acc, nbuf + mn * 528 + 256, bufB, bo, wt + 262144 + 256, bufB, off, q);
      barx();  // (2) n0 reads done (WAR)
#pragma unroll
      for (int nt = 0; nt < 2; ++nt) {
        const float bv = nt ? bv1b : bv1a;
#pragma unroll
        for (int r = 0; r < 4; ++r) {
          float v = fmaxf(acc[nt][r] + bv, 0.f) + n0v[nt][r];
          n1v[nt][r] = v;
          *(f16*)(nbuf + (dr + r) * 528 + (nc + nt * 16) * 2) = (f16)v;
        }
      }
      barx();  // (3) n1 visible

      // ---- m2: n2 = sigmoid(n1@Wh0[2] + b0[2]) + n0 ; prefetch Win1[t]
      acc[0] = zero4; acc[1] = zero4;
      phase<8, true>(acc, nbuf + mn * 528,       bufA, bo, wit,       bufA, off, q);
      phase<8, true>(acc, nbuf + mn * 528 + 256, bufB, bo, wit + 256, bufB, off, q);
      // epi2: h0' = 0.5(n1 + n2) -> abuf (LDS); final hidden out at last t
#pragma unroll
      for (int nt = 0; nt < 2; ++nt) {
        const float bv = nt ? bv2b : bv2a;
#pragma unroll
        for (int r = 0; r < 4; ++r) {
          float s = sigmoid_fast(acc[nt][r] + bv);
          float hv = 0.5f * (n1v[nt][r] + s + n0v[nt][r]);
          *(f16*)(abuf + (dr + r) * 528 + (nc + nt * 16) * 2) = (f16)hv;
          if (last) out[2097152 + (size_t)(rb + dr + r) * 256 + nc + nt * 16] = hv;
        }
      }
      barx();  // (4) h0' visible to all waves

      // ---- m3 (migrated): p3 = h0'@Win1[t] + b1[0]; no DMA
      // FIFO at m3A: [WinA 8][WinB 8] -> NW=8; m3B: NW=0
      acc[0] = zero4; acc[1] = zero4;
      phase<8, false>(acc, abuf + mn * 528,       bufA, bo, wt, bufA, off, q);
      phase<0, false>(acc, abuf + mn * 528 + 256, bufB, bo, wt, bufB, off, q);
      // epi3: publish p3 (f32, 16 KB)
#pragma unroll
      for (int nt = 0; nt < 2; ++nt) {
        const float bv = nt ? p3bb : p3ba;
#pragma unroll
        for (int r = 0; r < 4; ++r)
          p3seq[(size_t)(g * 64 + t) * 4096 + (dr + r) * 256 + nc + nt * 16] =
              acc[nt][r] + bv;
      }
      waitvm<0>();          // only the 8 p3 stores outstanding -- cheap drain
      __threadfence();      // device-scope release of data
      __syncthreads();      // all waves' stores complete
      if (tid == 0) {
        __hip_atomic_store(&flags[g * 64 + t], FLAG_MAGIC | (t + 1),
                           __ATOMIC_RELEASE, __HIP_MEMORY_SCOPE_AGENT);
      }
      sb();
      // prefetch next step's Wh0[0] halves
      {
        const char* gw = wtn;
#pragma unroll
        for (int d = 0; d < 8; ++d) dma16(gw + off[d], bufA + d * 1024);
#pragma unroll
        for (int d = 0; d < 8; ++d) dma16(gw + 256 + off[d], bufB + d * 1024);
        sb();
      }
    }
  } else {
    // =================== LAYER-1 CONSUMER (384 KB/t) ===================
    const char* WH = (const char*)Wh1T;   // [t][3][256][256]
    const float* p3g = p3seq + (size_t)g * 64 * 4096;
    { // prelude: DMA Wh1[0](t=0) halves; drain for t=0 m4 residency
      const char* gw = WH + wslice;
#pragma unroll
      for (int d = 0; d < 8; ++d) dma16(gw + off[d], bufA + d * 1024);
#pragma unroll
      for (int d = 0; d < 8; ++d) dma16(gw + 256 + off[d], bufB + d * 1024);
      sb();
      waitvm<0>();
    }
    barx();

#pragma unroll 1
    for (int t = 0; t < Tt; ++t) {
      const int tn = (t < Tt - 1) ? t + 1 : t;
      const bool last = (t == Tt - 1);
      const char* wht = WH + (size_t)t * 393216 + wslice;
      const char* whn = WH + (size_t)tn * 393216 + wslice;

      f32x4 acc[2];
      acc[0] = zero4; acc[1] = zero4;
      // ---- m4 FIRST (needs nothing from producer): h1@Wh1[0]; prefetch Wh1[1]
      // FIFO entering (t>0): [W0A 8][W0B 8][stores ~8] -> NW=17 then NW=9.
      // t=0: prelude drained -> no-ops.
      phase<17, true>(acc, abuf + mn * 528,       bufA, bo, wht + 131072,       bufA, off, q);
      phase<9,  true>(acc, abuf + mn * 528 + 256, bufB, bo, wht + 131072 + 256, bufB, off, q);

      // ---- poll producer flag (acquire; drains vmcnt -> W1A/W1B resident)
      {
        const int want = FLAG_MAGIC | (t + 1);
        while (__hip_atomic_load(&flags[g * 64 + t], __ATOMIC_ACQUIRE,
                                 __HIP_MEMORY_SCOPE_AGENT) != want) {}
      }
      sb();
      // p3(t) [8 f32 loads] + biases [4]
      float p3v[2][4];
#pragma unroll
      for (int nt = 0; nt < 2; ++nt)
#pragma unroll
        for (int r = 0; r < 4; ++r)
          p3v[nt][r] = p3g[(size_t)t * 4096 + (dr + r) * 256 + nc + nt * 16];
      const float bv1a = b1[(size_t)t * 768 + 256 + nc], bv1b = b1[(size_t)t * 768 + 256 + nc + 16];
      const float bv2a = b1[(size_t)t * 768 + 512 + nc], bv2b = b1[(size_t)t * 768 + 512 + nc + 16];
      sb();
      waitvm<0>();   // p3+bias landed (only those outstanding post-acquire)
      sb();
      // epi0': n0' = tanh(m4 + p3)
#pragma unroll
      for (int nt = 0; nt < 2; ++nt)
#pragma unroll
        for (int r = 0; r < 4; ++r) {
          float v = tanh_fast(acc[nt][r] + p3v[nt][r]);
          n0v[nt][r] = v;
          *(f16*)(nbuf + (dr + r) * 528 + (nc + nt * 16) * 2) = (f16)v;
        }
      barx();  // (1) n0' visible

      // ---- m5: n1' = relu(n0'@Wh1[1] + b1[1]) + n0' ; prefetch Wh1[2]
      // bufA/bufB resident via acquire drain -> NW=63 no-op
      acc[0] = zero4; acc[1] = zero4;
      phase<63, true>(acc, nbuf + mn * 528,       bufA, bo, wht + 262144,       bufA, off, q);
      phase<63, true>(acc, nbuf + mn * 528 + 256, bufB, bo, wht + 262144 + 256, bufB, off, q);
      barx();  // (2) n0' reads done (WAR)
#pragma unroll
      for (int nt = 0; nt < 2; ++nt) {
        const float bv = nt ? bv1b : bv1a;
#pragma unroll
        for (int r = 0; r < 4; ++r) {
          float v = fmaxf(acc[nt][r] + bv, 0.f) + n0v[nt][r];
          n1v[nt][r] = v;
          *(f16*)(nbuf + (dr + r) * 528 + (nc + nt * 16) * 2) = (f16)v;
        }
      }
      barx();  // (3) n1' visible

      // ---- m6: n2' = sigmoid(n1'@Wh1[2] + b1[2]) + n0' ; prefetch next Wh1[0]
      // FIFO at m6A: [W2A 8][W2B 8] -> NW=8; m6B: [W2B 8][W0An 8] -> NW=8
      acc[0] = zero4; acc[1] = zero4;
      phase<8, true>(acc, nbuf + mn * 528,       bufA, bo, whn,       bufA, off, q);
      phase<8, true>(acc, nbuf + mn * 528 + 256, bufB, bo, whn + 256, bufB, off, q);
#pragma unroll
      for (int nt = 0; nt < 2; ++nt) {
        const float bv = nt ? bv2b : bv2a;
#pragma unroll
        for (int r = 0; r < 4; ++r) {
          float s = sigmoid_fast(acc[nt][r] + bv);
          float hv = 0.5f * (n1v[nt][r] + s + n0v[nt][r]);
          *(f16*)(abuf + (dr + r) * 528 + (nc + nt * 16) * 2) = (f16)hv;
          out[((size_t)(rb + dr + r) * Tt + t) * 256 + nc + nt * 16] = hv;
          if (last) out[2097152 + 32768 + (size_t)(rb + dr + r) * 256 + nc + nt * 16] = hv;
        }
      }
      barx();  // (4) step end: h1' visible, nbuf reads done
    }
  }
}

// ---------------- launch ----------------
extern "C" void kernel_launch(void* const* d_in, const int* in_sizes, int n_in,
                              void* d_out, int out_size, void* d_ws, size_t ws_size,
                              hipStream_t stream) {
  (void)in_sizes; (void)n_in; (void)out_size; (void)ws_size;
  const float* x      = (const float*)d_in[0];
  const float* hidden = (const float*)d_in[1];
  const float* Win0   = (const float*)d_in[2];
  const float* Wh0    = (const float*)d_in[3];
  const float* b0     = (const float*)d_in[4];
  const float* Win1   = (const float*)d_in[5];
  const float* Wh1    = (const float*)d_in[6];
  const float* b1     = (const float*)d_in[7];
  float* out = (float*)d_out;

  char* ws = (char*)d_ws;
  f16* Wh0T   = (f16*)(ws + WS_WH0T);
  f16* Win1T  = (f16*)(ws + WS_WIN1T);
  f16* Wh1T   = (f16*)(ws + WS_WH1T);
  f16* Win0T  = (f16*)(ws + WS_WIN0T);
  float* xwp  = (float*)(ws + WS_XW);
  float* p3p  = (float*)(ws + WS_P3);
  int* flags  = (int*)(ws + WS_FLAGS);

  transpose_cvt_kernel<<<dim3(4096), dim3(256), 0, stream>>>(
      Wh0, Win1, Wh1, Win0, Wh0T, Win1T, Wh1T, Win0T);
  xw_kernel<<<dim3(512), dim3(512), 0, stream>>>(x, Win0T, b0, xwp);
  rnn_kernel<<<dim3(16), dim3(512), 0, stream>>>(
      hidden, Wh0T, b0, Win1T, Wh1T, b1, xwp, p3p, flags, out);
}

// Round 6
// 685.026 us; speedup vs baseline: 1.2918x; 1.1745x over previous
//
#include <hip/hip_runtime.h>

// CustomRNN: B=128, T=64, D=H=256, L=2, 3-node cell.
// Round 11: TRUE 448/448 BALANCE via K-split of m3 + publish-tax cut.
// Evidence r4..r10: rnn time = pacer bytes/t / ~22-30 B/cyc (per-CU
// global_load_lds law; r10's 512/384 rebalance was a null -- max() invariant).
// - Producer (L0): m0,m1,m2 + m3a = h0'@Win1[k-lo] (64KB/t). Publishes
//   p3a (16KB f32, incl b1[0]) + h0' k-hi half (4KB f16).  448KB/t.
// - Consumer (L1): m4 + m3b = h0'hi@Win1[k-hi] (64KB/t, A from published
//   half, r5-proven af pattern) + m5,m6.  n0' = tanh(m4+m3b+p3a). 448KB/t.
// - Both sides: clean 2-buffer rotation, 7 phase-DMAs = 7 phases per t,
//   pointers swapped per t. Full vmcnt ledger re-derived (annotated).
// - Publish: drop the all-thread __threadfence (8 redundant wbl2/t!);
//   per-wave counted store-retire + syncthreads + single tid0 RELEASE store;
//   W0hi' prefetch issued AFTER the flag store so it survives the publish.
// - Consumer poll: r10's acquire loop verbatim (proven; no new sync risk).

typedef _Float16 f16;
typedef __attribute__((ext_vector_type(8))) _Float16 f16x8;
typedef __attribute__((ext_vector_type(4))) float f32x4;
typedef __attribute__((ext_vector_type(4))) float float4v;

#define Tt 64
#define FLAG_MAGIC 0x52570000

// ---- workspace byte offsets ----
// Wh0T f16 25,165,824 | Win1T f16 8,388,608 | Wh1T f16 25,165,824
// Win0T f16 8,388,608 | xw f32 8,388,608 | p3a f32 8,388,608
// hseqh f16 2,097,152 | flags 2,048   => ~86 MB
#define WS_WH0T   0
#define WS_WIN1T  25165824
#define WS_WH1T   33554432
#define WS_WIN0T  58720256
#define WS_XW     67108864
#define WS_P3A    75497472
#define WS_HSEQH  83886080
#define WS_FLAGS  85983232

// ---------------- helpers ----------------
__device__ __forceinline__ void sb() { __builtin_amdgcn_sched_barrier(0); }

template <int N>
__device__ __forceinline__ void waitvm() {
  // s_waitcnt vmcnt(N), lgkm=15 (no wait), exp=7 (no wait); gfx9 encoding
  __builtin_amdgcn_s_waitcnt(0x0F70 | (N & 15) | ((N >> 4) << 14));
}
__device__ __forceinline__ void waitlgkm0() { __builtin_amdgcn_s_waitcnt(0xC07F); }

__device__ __forceinline__ void barx() {
  // barrier draining LDS ops only -- weight DMAs (vmcnt) stay in flight
  asm volatile("s_waitcnt lgkmcnt(0)\n\ts_barrier" ::: "memory");
}

__device__ __forceinline__ void dma16(const void* g, void* l) {
  __builtin_amdgcn_global_load_lds(
      (const __attribute__((address_space(1))) unsigned int*)g,
      (__attribute__((address_space(3))) unsigned int*)l, 16, 0, 0);
}

__device__ __forceinline__ float tanh_fast(float x) {
  float xc = fminf(fmaxf(x, -15.f), 15.f);
  float e = __expf(2.f * xc);
  return (e - 1.f) / (e + 1.f);
}
__device__ __forceinline__ float sigmoid_fast(float x) { return 1.f / (1.f + __expf(-x)); }

// ---------------- transpose+convert: [k][n] f32 -> [n][k] f16 ----------------
// 512 matrices: 192 Wh0 + 64 Win1 + 192 Wh1 + 64 Win0
__global__ __launch_bounds__(256) void transpose_cvt_kernel(
    const float* __restrict__ Wh0, const float* __restrict__ Win1,
    const float* __restrict__ Wh1, const float* __restrict__ Win0,
    f16* __restrict__ Wh0T, f16* __restrict__ Win1T, f16* __restrict__ Wh1T,
    f16* __restrict__ Win0T) {
  __shared__ float tile[256 * 33];
  const int bid = blockIdx.x;
  const int mat = bid >> 3, n0 = (bid & 7) << 5;
  const float* src; f16* dst;
  if (mat < 192)      { src = Wh0  + (size_t)mat * 65536;         dst = Wh0T  + (size_t)mat * 65536; }
  else if (mat < 256) { src = Win1 + (size_t)(mat - 192) * 65536; dst = Win1T + (size_t)(mat - 192) * 65536; }
  else if (mat < 448) { src = Wh1  + (size_t)(mat - 256) * 65536; dst = Wh1T  + (size_t)(mat - 256) * 65536; }
  else                { src = Win0 + (size_t)(mat - 448) * 65536; dst = Win0T + (size_t)(mat - 448) * 65536; }
  const int tid = threadIdx.x;
  const int c2 = tid & 15, kl = tid >> 4;
#pragma unroll
  for (int p = 0; p < 16; ++p) {
    const int k = kl + p * 16;
    float2 v = *(const float2*)(src + k * 256 + n0 + c2 * 2);
    tile[k * 33 + c2 * 2]     = v.x;
    tile[k * 33 + c2 * 2 + 1] = v.y;
  }
  __syncthreads();
  // store phase: 32 consecutive lanes cover one n-row's 512 contiguous bytes
  const int n = tid >> 5, c = tid & 31;
#pragma unroll
  for (int it = 0; it < 4; ++it) {
    const int nn = n + it * 8;
    f16x8 vv;
#pragma unroll
    for (int i = 0; i < 8; ++i) vv[i] = (f16)tile[(c * 8 + i) * 33 + nn];
    *(f16x8*)((char*)dst + (size_t)(n0 + nn) * 512 + c * 16) = vv;
  }
}

// ---------------- xw precompute: xw[t,b,h] = x[b,t,:]@Win0[t] + b0[t,0,h] ----
__global__ __launch_bounds__(512, 2) void xw_kernel(
    const float* __restrict__ x, const f16* __restrict__ Win0T,
    const float* __restrict__ b0, float* __restrict__ xw) {
  const int t = blockIdx.x >> 3, bb = blockIdx.x & 7;
  const int rb = bb << 4;
  const int tid = threadIdx.x, lane = tid & 63, w = tid >> 6;
  const int q = lane >> 4, mn = lane & 15, dr = q * 4;
  const f16* wt = Win0T + (size_t)t * 65536;
  const float4v* xr = (const float4v*)(x + ((size_t)(rb + mn) * Tt + t) * 256);
  f32x4 acc[2] = {{0.f,0.f,0.f,0.f},{0.f,0.f,0.f,0.f}};
#pragma unroll
  for (int kt = 0; kt < 8; ++kt) {
    const int k0 = kt * 32 + q * 8;
    float4v x0 = xr[k0 / 4], x1 = xr[k0 / 4 + 1];
    f16x8 a = {(f16)x0.x, (f16)x0.y, (f16)x0.z, (f16)x0.w,
               (f16)x1.x, (f16)x1.y, (f16)x1.z, (f16)x1.w};
#pragma unroll
    for (int nt = 0; nt < 2; ++nt) {
      f16x8 b = *(const f16x8*)(wt + (size_t)(w * 32 + nt * 16 + mn) * 256 + k0);
      acc[nt] = __builtin_amdgcn_mfma_f32_16x16x32_f16(a, b, acc[nt], 0, 0, 0);
    }
  }
#pragma unroll
  for (int nt = 0; nt < 2; ++nt) {
    const int n = w * 32 + nt * 16 + mn;
    const float bv = b0[(size_t)t * 768 + n];
#pragma unroll
    for (int r = 0; r < 4; ++r)
      xw[(size_t)t * 32768 + (size_t)(rb + dr + r) * 256 + n] = acc[nt][r] + bv;
  }
}

// ---------------- matmul K-half phase (A from LDS) ----------------
template <int NW, bool DMA>
__device__ __forceinline__ void phase(f32x4 (&acc)[2], const char* arow, const char* wb,
                                      const int (&bo)[4], const char* gnext, char* lnext,
                                      const int (&off)[8], int q) {
  waitvm<NW>();
  sb();
  f16x8 a[4], b[8];
#pragma unroll
  for (int kt = 0; kt < 4; ++kt) {
    a[kt]         = *(const f16x8*)(arow + kt * 64 + q * 16);
    b[kt * 2]     = *(const f16x8*)(wb + bo[kt]);
    b[kt * 2 + 1] = *(const f16x8*)(wb + bo[kt] + 4096);
  }
  sb();
  waitlgkm0();
  if (DMA) {
#pragma unroll
    for (int d = 0; d < 8; ++d) dma16(gnext + off[d], lnext + d * 1024);
  }
  sb();
#pragma unroll
  for (int kt = 0; kt < 4; ++kt) {
    acc[0] = __builtin_amdgcn_mfma_f32_16x16x32_f16(a[kt], b[kt * 2],     acc[0], 0, 0, 0);
    acc[1] = __builtin_amdgcn_mfma_f32_16x16x32_f16(a[kt], b[kt * 2 + 1], acc[1], 0, 0, 0);
  }
}

// ---------------- recurrent kernel: 16 WGs (8 L0 + 8 L1), 16 rows each ------
__global__ __launch_bounds__(512, 1) void rnn_kernel(
    const float* __restrict__ hidden,
    const f16* __restrict__ Wh0T, const float* __restrict__ b0,
    const f16* __restrict__ Win1T, const f16* __restrict__ Wh1T, const float* __restrict__ b1,
    const float* __restrict__ xw, float* __restrict__ p3a, f16* __restrict__ hseqh,
    int* __restrict__ flags, float* __restrict__ out) {
  __shared__ __align__(16) char smem[147968];
  char* wlds = smem;                 // 8 waves x 16 KB (two 8KB buffers)
  char* abuf = smem + 131072;        // recurrent h (h0 for L0 / h1 for L1)
  char* nbuf = smem + 139520;

  const int tid = threadIdx.x;
  const int lane = tid & 63;
  const int w = tid >> 6;
  const int q = lane >> 4;
  const int mn = lane & 15;
  const bool isL0 = blockIdx.x < 8;
  const int g = blockIdx.x & 7;
  const int rb = g << 4;
  const int nc = w * 32 + mn;
  const int dr = q * 4;
  const int wslice = w * 16384;

  int off[8], bo[4];
#pragma unroll
  for (int d = 0; d < 8; ++d) {
    const int row = 4 * d + q;
    off[d] = row * 512 + ((mn ^ (row & 15)) << 4);
  }
#pragma unroll
  for (int kt = 0; kt < 4; ++kt)
    bo[kt] = mn * 256 + (((kt * 4 + q) ^ mn) << 4);

  // init recurrent state (layer-appropriate half of hidden)
  const float* hsrc = hidden + (isL0 ? 0 : 32768) + (size_t)rb * 256;
  for (int i = tid; i < 16 * 256; i += 512) {
    const int m = i >> 8, n = i & 255;
    *(f16*)(abuf + m * 528 + n * 2) = (f16)hsrc[m * 256 + n];
  }

  char* pA = wlds + wslice;
  char* pB = pA + 8192;
  const f32x4 zero4 = {0.f, 0.f, 0.f, 0.f};
  float n0v[2][4], n1v[2][4];

  if (isL0) {
    // =================== LAYER-0 PRODUCER (448 KB/t) ===================
    const char* WB = (const char*)Wh0T;   // [t][3][256n][256k] f16
    const char* WI = (const char*)Win1T;  // [t][256n][256k]
    { // prelude: DMA Wh0[0](t=0) halves; drain for t=0 residency
      const char* gw = WB + wslice;
#pragma unroll
      for (int d = 0; d < 8; ++d) dma16(gw + off[d], pA + d * 1024);
#pragma unroll
      for (int d = 0; d < 8; ++d) dma16(gw + 256 + off[d], pB + d * 1024);
      sb();
      waitvm<0>();
    }
    barx();

#pragma unroll 1
    for (int t = 0; t < Tt; ++t) {
      const int tn = (t < Tt - 1) ? t + 1 : t;
      const bool last = (t == Tt - 1);
      const char* wt  = WB + (size_t)t * 393216 + wslice;
      const char* wtn = WB + (size_t)tn * 393216 + wslice;
      const char* wit = WI + (size_t)t * 131072 + wslice;

      // loop top: xw 8 + b0[1] 2 + b0[2] 2 + b1[0] 2 = 14 loads
      float xwv[2][4];
#pragma unroll
      for (int nt = 0; nt < 2; ++nt)
#pragma unroll
        for (int r = 0; r < 4; ++r)
          xwv[nt][r] = xw[(size_t)t * 32768 + (size_t)(rb + dr + r) * 256 + nc + nt * 16];
      const float bv1a = b0[(size_t)t * 768 + 256 + nc], bv1b = b0[(size_t)t * 768 + 256 + nc + 16];
      const float bv2a = b0[(size_t)t * 768 + 512 + nc], bv2b = b0[(size_t)t * 768 + 512 + nc + 16];
      const float p3ba = b1[(size_t)t * 768 + nc],       p3bb = b1[(size_t)t * 768 + nc + 16];
      sb();

      f32x4 acc[2];
      // ---- m0: n0 = tanh(h0@Wh0[0] + xw)
      // entry FIFO: [W0hi' 8] + ld14 = 22 -> m0A NW=22 no-op (W0lo retired
      // pre-publish last t); m0A dma W1lo. m0B: [W0hi][ld14][W1lo]=30 ->
      // NW=22 retires W0hi. m0B dma W1hi.
      acc[0] = zero4; acc[1] = zero4;
      phase<22, true>(acc, abuf + mn * 528,       pA, bo, wt + 131072,       pA, off, q);
      phase<22, true>(acc, abuf + mn * 528 + 256, pB, bo, wt + 131072 + 256, pB, off, q);
      // retire the 14 loads: [ld14][W1lo 8][W1hi 8]=30 -> NW=16
      waitvm<16>();
      sb();
#pragma unroll
      for (int nt = 0; nt < 2; ++nt)
#pragma unroll
        for (int r = 0; r < 4; ++r) {
          float v = tanh_fast(acc[nt][r] + xwv[nt][r]);
          n0v[nt][r] = v;
          *(f16*)(nbuf + (dr + r) * 528 + (nc + nt * 16) * 2) = (f16)v;
        }
      barx();  // (1) n0 visible

      // ---- m1: n1 = relu(n0@Wh0[1] + b0[1]) + n0
      // m1A: [W1lo][W1hi] NW=8, dma W2lo. m1B: [W1hi][W2lo] NW=8, dma W2hi.
      acc[0] = zero4; acc[1] = zero4;
      phase<8, true>(acc, nbuf + mn * 528,       pA, bo, wt + 262144,       pA, off, q);
      phase<8, true>(acc, nbuf + mn * 528 + 256, pB, bo, wt + 262144 + 256, pB, off, q);
      barx();  // (2) n0 reads done (WAR)
#pragma unroll
      for (int nt = 0; nt < 2; ++nt) {
        const float bv = nt ? bv1b : bv1a;
#pragma unroll
        for (int r = 0; r < 4; ++r) {
          float v = fmaxf(acc[nt][r] + bv, 0.f) + n0v[nt][r];
          n1v[nt][r] = v;
          *(f16*)(nbuf + (dr + r) * 528 + (nc + nt * 16) * 2) = (f16)v;
        }
      }
      barx();  // (3) n1 visible

      // ---- m2: n2 = sigmoid(n1@Wh0[2] + b0[2]) + n0
      // m2A: [W2lo][W2hi] NW=8, dma WinLo. m2B: [W2hi][WinLo] NW=8, dma W0lo'.
      acc[0] = zero4; acc[1] = zero4;
      phase<8, true>(acc, nbuf + mn * 528,       pA, bo, wit, pA, off, q);
      phase<8, true>(acc, nbuf + mn * 528 + 256, pB, bo, wtn, pB, off, q);
      // epi2: h0' = 0.5(n1+n2) -> abuf; last-t hidden out
#pragma unroll
      for (int nt = 0; nt < 2; ++nt) {
        const float bv = nt ? bv2b : bv2a;
#pragma unroll
        for (int r = 0; r < 4; ++r) {
          float s = sigmoid_fast(acc[nt][r] + bv);
          float hv = 0.5f * (n1v[nt][r] + s + n0v[nt][r]);
          *(f16*)(abuf + (dr + r) * 528 + (nc + nt * 16) * 2) = (f16)hv;
          if (last) out[2097152 + (size_t)(rb + dr + r) * 256 + nc + nt * 16] = hv;
        }
      }
      barx();  // (4) h0' visible to all waves

      // ---- m3a: p3a = h0'(k-lo) @ Win1[k-lo] + b1[0]
      // [WinLo 8][W0lo' 8] -> NW=8 retires WinLo. No phase-DMA here.
      waitvm<8>();
      sb();
      {
        f16x8 a3[4], b3[8];
#pragma unroll
        for (int kt = 0; kt < 4; ++kt) {
          a3[kt]         = *(const f16x8*)(abuf + mn * 528 + kt * 64 + q * 16);
          b3[kt * 2]     = *(const f16x8*)(pA + bo[kt]);
          b3[kt * 2 + 1] = *(const f16x8*)(pA + bo[kt] + 4096);
        }
        sb();
        waitlgkm0();
        sb();
        acc[0] = zero4; acc[1] = zero4;
#pragma unroll
        for (int kt = 0; kt < 4; ++kt) {
          acc[0] = __builtin_amdgcn_mfma_f32_16x16x32_f16(a3[kt], b3[kt * 2],     acc[0], 0, 0, 0);
          acc[1] = __builtin_amdgcn_mfma_f32_16x16x32_f16(a3[kt], b3[kt * 2 + 1], acc[1], 0, 0, 0);
        }
      }
      // publish stores: p3a (8 f32, all waves) + h0' k-hi (8 f16, waves 4-7)
#pragma unroll
      for (int nt = 0; nt < 2; ++nt) {
        const float bv = nt ? p3bb : p3ba;
#pragma unroll
        for (int r = 0; r < 4; ++r)
          p3a[(size_t)(g * 64 + t) * 4096 + (dr + r) * 256 + nc + nt * 16] = acc[nt][r] + bv;
      }
      if (w >= 4) {
        char* hs = (char*)hseqh + (size_t)(g * 64 + t) * 4096;
#pragma unroll
        for (int nt = 0; nt < 2; ++nt)
#pragma unroll
          for (int r = 0; r < 4; ++r)
            *(f16*)(hs + (dr + r) * 256 + (nc + nt * 16 - 128) * 2) =
                *(f16*)(abuf + (dr + r) * 528 + (nc + nt * 16) * 2);
      }
      sb();
      // retire stores (+W0lo', old): FIFO [W0lo'][stores] -> vmcnt(0), cheap
      waitvm<0>();
      __syncthreads();
      if (tid == 0) {
        __hip_atomic_store(&flags[g * 64 + t], FLAG_MAGIC | (t + 1),
                           __ATOMIC_RELEASE, __HIP_MEMORY_SCOPE_AGENT);
      }
      sb();
      // W0hi' prefetch AFTER publish -> survives it; entry ledger next t: [8]
      {
#pragma unroll
        for (int d = 0; d < 8; ++d) dma16(wtn + 256 + off[d], pA + d * 1024);
        sb();
      }
      { char* tp = pA; pA = pB; pB = tp; }  // W0lo' in old pB -> new pA
    }
  } else {
    // =================== LAYER-1 CONSUMER (448 KB/t) ===================
    const char* WH = (const char*)Wh1T;   // [t][3][256n][256k]
    const char* WI = (const char*)Win1T;  // [t][256n][256k]
    const float* p3g = p3a + (size_t)g * 64 * 4096;
    const char* hsg = (const char*)hseqh + (size_t)g * 64 * 4096;
    { // prelude: DMA Wh1[0](t=0) halves; drain
      const char* gw = WH + wslice;
#pragma unroll
      for (int d = 0; d < 8; ++d) dma16(gw + off[d], pA + d * 1024);
#pragma unroll
      for (int d = 0; d < 8; ++d) dma16(gw + 256 + off[d], pB + d * 1024);
      sb();
      waitvm<0>();
    }
    barx();

#pragma unroll 1
    for (int t = 0; t < Tt; ++t) {
      const int tn = (t < Tt - 1) ? t + 1 : t;
      const bool last = (t == Tt - 1);
      const char* wht = WH + (size_t)t * 393216 + wslice;
      const char* whn = WH + (size_t)tn * 393216 + wslice;
      const char* wit = WI + (size_t)t * 131072 + wslice;

      // loop top: b1[1] 2 + b1[2] 2 = 4 loads
      const float bv1a = b1[(size_t)t * 768 + 256 + nc], bv1b = b1[(size_t)t * 768 + 256 + nc + 16];
      const float bv2a = b1[(size_t)t * 768 + 512 + nc], bv2b = b1[(size_t)t * 768 + 512 + nc + 16];
      sb();

      f32x4 acc[2];
      acc[0] = zero4; acc[1] = zero4;
      // ---- m4: h1@Wh1[0] (needs nothing from producer)
      // entry: [W0lo 8][W0hi 8][out8? (t>0)][ld4]; m4A NW=12 retires W0lo(+),
      // dma WinHi. m4B NW=12 retires rest-but-12, dma W1lo.
      phase<12, true>(acc, abuf + mn * 528,       pA, bo, wit + 256,    pA, off, q);
      phase<12, true>(acc, abuf + mn * 528 + 256, pB, bo, wht + 131072, pB, off, q);

      // ---- poll producer flag (acquire; implicit drain retires WinHi/W1lo)
      {
        const int want = FLAG_MAGIC | (t + 1);
        while (__hip_atomic_load(&flags[g * 64 + t], __ATOMIC_ACQUIRE,
                                 __HIP_MEMORY_SCOPE_AGENT) != want) {}
      }
      sb();
      // h0' k-hi A-fragments (4) + p3a (8) -- post-acquire, plain loads
      const char* ht = hsg + (size_t)t * 4096;
      f16x8 af[4];
#pragma unroll
      for (int kt = 0; kt < 4; ++kt)
        af[kt] = *(const f16x8*)(ht + mn * 256 + kt * 64 + q * 16);
      float p3v[2][4];
#pragma unroll
      for (int nt = 0; nt < 2; ++nt)
#pragma unroll
        for (int r = 0; r < 4; ++r)
          p3v[nt][r] = p3g[(size_t)t * 4096 + (dr + r) * 256 + nc + nt * 16];
      sb();

      // ---- m3b: h0'hi @ Win1[k-hi] (B=pA resident via acquire drain);
      //      dma W1hi -> pA. Accumulates into the SAME acc as m4.
      {
        f16x8 b3[8];
#pragma unroll
        for (int kt = 0; kt < 4; ++kt) {
          b3[kt * 2]     = *(const f16x8*)(pA + bo[kt]);
          b3[kt * 2 + 1] = *(const f16x8*)(pA + bo[kt] + 4096);
        }
        sb();
        waitlgkm0();
#pragma unroll
        for (int d = 0; d < 8; ++d) dma16(wht + 131072 + 256 + off[d], pA + d * 1024);
        sb();
#pragma unroll
        for (int kt = 0; kt < 4; ++kt) {
          acc[0] = __builtin_amdgcn_mfma_f32_16x16x32_f16(af[kt], b3[kt * 2],     acc[0], 0, 0, 0);
          acc[1] = __builtin_amdgcn_mfma_f32_16x16x32_f16(af[kt], b3[kt * 2 + 1], acc[1], 0, 0, 0);
        }
      }
      // epi0': n0' = tanh(m4 + m3b + p3a)
#pragma unroll
      for (int nt = 0; nt < 2; ++nt)
#pragma unroll
        for (int r = 0; r < 4; ++r) {
          float v = tanh_fast(acc[nt][r] + p3v[nt][r]);
          n0v[nt][r] = v;
          *(f16*)(nbuf + (dr + r) * 528 + (nc + nt * 16) * 2) = (f16)v;
        }
      barx();  // (1) n0' visible

      // ---- m5: n1' = relu(n0'@Wh1[1] + b1[1]) + n0'
      // m5A: B=W1lo (pB, resident via acquire drain) NW=63 no-op, dma W2lo.
      // m5B: B=W1hi (pA): [af+p3 12][W1hi 8][W2lo 8]=28 -> NW=8 retires W1hi.
      acc[0] = zero4; acc[1] = zero4;
      phase<63, true>(acc, nbuf + mn * 528,       pB, bo, wht + 262144,       pB, off, q);
      phase<8,  true>(acc, nbuf + mn * 528 + 256, pA, bo, wht + 262144 + 256, pA, off, q);
      barx();  // (2) n0' reads done (WAR)
#pragma unroll
      for (int nt = 0; nt < 2; ++nt) {
        const float bv = nt ? bv1b : bv1a;
#pragma unroll
        for (int r = 0; r < 4; ++r) {
          float v = fmaxf(acc[nt][r] + bv, 0.f) + n0v[nt][r];
          n1v[nt][r] = v;
          *(f16*)(nbuf + (dr + r) * 528 + (nc + nt * 16) * 2) = (f16)v;
        }
      }
      barx();  // (3) n1' visible

      // ---- m6: n2' = sigmoid(n1'@Wh1[2] + b1[2]) + n0'
      // m6A: [W2lo][W2hi] NW=8, dma W0lo'->pB. m6B: [W2hi][W0lo'] NW=8,
      // dma W0hi'->pA.
      acc[0] = zero4; acc[1] = zero4;
      phase<8, true>(acc, nbuf + mn * 528,       pB, bo, whn,       pB, off, q);
      phase<8, true>(acc, nbuf + mn * 528 + 256, pA, bo, whn + 256, pA, off, q);
#pragma unroll
      for (int nt = 0; nt < 2; ++nt) {
        const float bv = nt ? bv2b : bv2a;
#pragma unroll
        for (int r = 0; r < 4; ++r) {
          float s = sigmoid_fast(acc[nt][r] + bv);
          float hv = 0.5f * (n1v[nt][r] + s + n0v[nt][r]);
          *(f16*)(abuf + (dr + r) * 528 + (nc + nt * 16) * 2) = (f16)hv;
          out[((size_t)(rb + dr + r) * Tt + t) * 256 + nc + nt * 16] = hv;
          if (last) out[2097152 + 32768 + (size_t)(rb + dr + r) * 256 + nc + nt * 16] = hv;
        }
      }
      barx();  // (4) step end: h1' visible, nbuf reads done
      { char* tp = pA; pA = pB; pB = tp; }  // W0lo' in old pB -> new pA
    }
  }
}

// ---------------- launch ----------------
extern "C" void kernel_launch(void* const* d_in, const int* in_sizes, int n_in,
                              void* d_out, int out_size, void* d_ws, size_t ws_size,
                              hipStream_t stream) {
  (void)in_sizes; (void)n_in; (void)out_size; (void)ws_size;
  const float* x      = (const float*)d_in[0];
  const float* hidden = (const float*)d_in[1];
  const float* Win0   = (const float*)d_in[2];
  const float* Wh0    = (const float*)d_in[3];
  const float* b0     = (const float*)d_in[4];
  const float* Win1   = (const float*)d_in[5];
  const float* Wh1    = (const float*)d_in[6];
  const float* b1     = (const float*)d_in[7];
  float* out = (float*)d_out;

  char* ws = (char*)d_ws;
  f16* Wh0T   = (f16*)(ws + WS_WH0T);
  f16* Win1T  = (f16*)(ws + WS_WIN1T);
  f16* Wh1T   = (f16*)(ws + WS_WH1T);
  f16* Win0T  = (f16*)(ws + WS_WIN0T);
  float* xwp  = (float*)(ws + WS_XW);
  float* p3p  = (float*)(ws + WS_P3A);
  f16* hseqh  = (f16*)(ws + WS_HSEQH);
  int* flags  = (int*)(ws + WS_FLAGS);

  transpose_cvt_kernel<<<dim3(4096), dim3(256), 0, stream>>>(
      Wh0, Win1, Wh1, Win0, Wh0T, Win1T, Wh1T, Win0T);
  xw_kernel<<<dim3(512), dim3(512), 0, stream>>>(x, Win0T, b0, xwp);
  rnn_kernel<<<dim3(16), dim3(512), 0, stream>>>(
      hidden, Wh0T, b0, Win1T, Wh1T, b1, xwp, p3p, hseqh, flags, out);
}